// Round 1
// baseline (3999.365 us; speedup 1.0000x reference)
//
#include <hip/hip_runtime.h>
#include <math.h>

#define NN 50000
#define EE 800000
#define CC 192

// ============ GEMM: out[N,M] = A1@W1^T (+ A2@W2^T) + bias ============
// A row-major [N,K]; W row-major [M,K] (so W^T matmul = NT gemm, both K-contiguous)
__global__ __launch_bounds__(256) void gemm_nt(
    const float* __restrict__ A1, const float* __restrict__ W1,
    const float* __restrict__ A2, const float* __restrict__ W2,
    const float* __restrict__ bias, float* __restrict__ out,
    int Nrows, int K, int M)
{
    __shared__ float As[16][132];
    __shared__ float Bs[16][132];
    const int tid = threadIdx.x;
    const int row0 = blockIdx.y * 128;
    const int col0 = blockIdx.x * 128;
    const int ty = tid / 16, tx = tid % 16;

    float acc[8][8];
#pragma unroll
    for (int i = 0; i < 8; ++i)
#pragma unroll
        for (int j = 0; j < 8; ++j) acc[i][j] = 0.f;

    const int lr = tid >> 2;          // 0..63
    const int lk = (tid & 3) * 4;     // 0,4,8,12

    const int npass = A2 ? 2 : 1;
    for (int pass = 0; pass < npass; ++pass) {
        const float* __restrict__ A = pass ? A2 : A1;
        const float* __restrict__ W = pass ? W2 : W1;
        for (int k0 = 0; k0 < K; k0 += 16) {
#pragma unroll
            for (int h = 0; h < 2; ++h) {
                int r = row0 + lr + h * 64;
                int rc = r < Nrows ? r : Nrows - 1;
                float4 av = *reinterpret_cast<const float4*>(&A[(size_t)rc * K + k0 + lk]);
                As[lk + 0][lr + h * 64] = av.x;
                As[lk + 1][lr + h * 64] = av.y;
                As[lk + 2][lr + h * 64] = av.z;
                As[lk + 3][lr + h * 64] = av.w;
                int n = col0 + lr + h * 64;
                int nc = n < M ? n : M - 1;
                float4 wv = *reinterpret_cast<const float4*>(&W[(size_t)nc * K + k0 + lk]);
                Bs[lk + 0][lr + h * 64] = wv.x;
                Bs[lk + 1][lr + h * 64] = wv.y;
                Bs[lk + 2][lr + h * 64] = wv.z;
                Bs[lk + 3][lr + h * 64] = wv.w;
            }
            __syncthreads();
#pragma unroll
            for (int k = 0; k < 16; ++k) {
                float a[8], b[8];
#pragma unroll
                for (int i = 0; i < 8; ++i) a[i] = As[k][ty * 8 + i];
#pragma unroll
                for (int j = 0; j < 8; ++j) b[j] = Bs[k][tx * 8 + j];
#pragma unroll
                for (int i = 0; i < 8; ++i)
#pragma unroll
                    for (int j = 0; j < 8; ++j) acc[i][j] = fmaf(a[i], b[j], acc[i][j]);
            }
            __syncthreads();
        }
    }

#pragma unroll
    for (int i = 0; i < 8; ++i) {
        int r = row0 + ty * 8 + i;
        if (r >= Nrows) continue;
#pragma unroll
        for (int j = 0; j < 8; ++j) {
            int c = col0 + tx * 8 + j;
            if (c < M) out[(size_t)r * M + c] = acc[i][j] + bias[c];
        }
    }
}

// ============ column stats: sum & sumsq per column (2-stage atomic) ============
__global__ __launch_bounds__(256) void col_stats(
    const float* __restrict__ buf, int Nrows, int M,
    float* __restrict__ sum, float* __restrict__ sumsq)
{
    int col = blockIdx.x * 64 + (threadIdx.x & 63);
    int rg = threadIdx.x >> 6;  // 0..3
    int rows_per_chunk = (Nrows + gridDim.y - 1) / gridDim.y;
    int r0 = blockIdx.y * rows_per_chunk;
    int r1 = min(r0 + rows_per_chunk, Nrows);
    float s = 0.f, q = 0.f;
    for (int r = r0 + rg; r < r1; r += 4) {
        float v = buf[(size_t)r * M + col];
        s += v;
        q += v * v;
    }
    atomicAdd(&sum[col], s);
    atomicAdd(&sumsq[col], q);
}

__global__ void bn_finalize(const float* __restrict__ sum, const float* __restrict__ sumsq,
                            float* __restrict__ mu, float* __restrict__ rs, int M, float invN)
{
    int i = blockIdx.x * blockDim.x + threadIdx.x;
    if (i < M) {
        float m = sum[i] * invN;
        float v = sumsq[i] * invN - m * m;
        mu[i] = m;
        rs[i] = rsqrtf(v + 1e-5f);
    }
}

// ============ BN apply variants ============
__global__ __launch_bounds__(256) void bn_apply_inplace(
    float* __restrict__ buf, size_t total, int M,
    const float* __restrict__ g, const float* __restrict__ b,
    const float* __restrict__ mu, const float* __restrict__ rs)
{
    for (size_t i = (size_t)blockIdx.x * blockDim.x + threadIdx.x; i < total;
         i += (size_t)gridDim.x * blockDim.x) {
        int c = (int)(i % M);
        buf[i] = g[c] * (buf[i] - mu[c]) * rs[c] + b[c];
    }
}

__global__ __launch_bounds__(256) void bn_apply_gelu_inplace(
    float* __restrict__ buf, size_t total, int M,
    const float* __restrict__ g, const float* __restrict__ b,
    const float* __restrict__ mu, const float* __restrict__ rs)
{
    for (size_t i = (size_t)blockIdx.x * blockDim.x + threadIdx.x; i < total;
         i += (size_t)gridDim.x * blockDim.x) {
        int c = (int)(i % M);
        float v = g[c] * (buf[i] - mu[c]) * rs[c] + b[c];
        buf[i] = 0.5f * v * (1.f + erff(v * 0.70710678118654752f));
    }
}

__global__ __launch_bounds__(256) void bn_apply_residual(
    const float* __restrict__ pre, const float* __restrict__ res, float* __restrict__ out,
    size_t total, int M,
    const float* __restrict__ g, const float* __restrict__ b,
    const float* __restrict__ mu, const float* __restrict__ rs)
{
    for (size_t i = (size_t)blockIdx.x * blockDim.x + threadIdx.x; i < total;
         i += (size_t)gridDim.x * blockDim.x) {
        int c = (int)(i % M);
        out[i] = g[c] * (pre[i] - mu[c]) * rs[c] + b[c] + res[i];
    }
}

// ============ edge scatter: AGG[dst] += T[src], 256 channels ============
__global__ __launch_bounds__(256) void edge_scatter(
    const int* __restrict__ src, const int* __restrict__ dst,
    const float* __restrict__ T, float* __restrict__ AGG, int E)
{
    int e = blockIdx.x * 4 + (threadIdx.x >> 6);
    if (e >= E) return;
    int c0 = (threadIdx.x & 63) * 4;
    int s = src[e], d = dst[e];
    float4 v = *reinterpret_cast<const float4*>(&T[(size_t)s * 256 + c0]);
    float* p = &AGG[(size_t)d * 256 + c0];
    atomicAdd(p + 0, v.x);
    atomicAdd(p + 1, v.y);
    atomicAdd(p + 2, v.z);
    atomicAdd(p + 3, v.w);
}

// =====================================================================
extern "C" void kernel_launch(void* const* d_in, const int* in_sizes, int n_in,
                              void* d_out, int out_size, void* d_ws, size_t ws_size,
                              hipStream_t stream)
{
    const float* x        = (const float*)d_in[0];
    const int*   ei       = (const int*)d_in[1];
    const float* w_g1     = (const float*)d_in[2];
    const float* b_g1     = (const float*)d_in[3];
    const float* g1_gamma = (const float*)d_in[4];
    const float* g1_beta  = (const float*)d_in[5];
    const float* w_rel    = (const float*)d_in[6];
    const float* b_rel    = (const float*)d_in[7];
    const float* w_root   = (const float*)d_in[8];
    const float* w_g2     = (const float*)d_in[9];
    const float* b_g2     = (const float*)d_in[10];
    const float* g2_gamma = (const float*)d_in[11];
    const float* g2_beta  = (const float*)d_in[12];
    const float* w_f1     = (const float*)d_in[13];
    const float* b_f1     = (const float*)d_in[14];
    const float* f1_gamma = (const float*)d_in[15];
    const float* f1_beta  = (const float*)d_in[16];
    const float* w_f2     = (const float*)d_in[17];
    const float* b_f2     = (const float*)d_in[18];
    const float* f2_gamma = (const float*)d_in[19];
    const float* f2_beta  = (const float*)d_in[20];

    const int* src = ei;
    const int* dst = ei + EE;

    float* ws  = (float*)d_ws;
    float* T   = ws;                       // [N,256]
    float* AGG = T   + (size_t)NN * 256;   // [N,256]
    float* H   = AGG + (size_t)NN * 256;   // [N,512]
    float* X2  = H   + (size_t)NN * 512;   // [N,192]
    float* S   = X2  + (size_t)NN * 192;   // stats: sum|sumsq|mu|rs, 512 each
    float* sum   = S;
    float* sumsq = S + 512;
    float* mu    = S + 1024;
    float* rs    = S + 1536;
    float* Y  = AGG;  // y2 pre-BN  [N,192]   (AGG dead after step 5)
    float* F  = H;    // ffn hidden [N,512]   (H dead after step 6)
    float* F2 = T;    // f2 pre-BN  [N,192]   (T dead after step 5)

    float* out = (float*)d_out;
    const float invN = 1.f / (float)NN;
    dim3 blk(256);
    const int GY = (NN + 127) / 128;

    auto gemm = [&](const float* A1, const float* W1, const float* A2, const float* W2,
                    const float* bias, float* o, int K, int M) {
        dim3 grid((M + 127) / 128, GY);
        hipLaunchKernelGGL(gemm_nt, grid, blk, 0, stream, A1, W1, A2, W2, bias, o, NN, K, M);
    };
    auto stats = [&](const float* buf, int M) {
        hipMemsetAsync(sum, 0, 1024 * sizeof(float), stream);  // sum+sumsq
        dim3 grid(M / 64, 196);
        hipLaunchKernelGGL(col_stats, grid, blk, 0, stream, buf, NN, M, sum, sumsq);
        hipLaunchKernelGGL(bn_finalize, dim3(2), dim3(256), 0, stream, sum, sumsq, mu, rs, M, invN);
    };

    // ---- Grapher ----
    // 1. T = x @ w_g1^T + b_g1          [N,256]
    gemm(x, w_g1, nullptr, nullptr, b_g1, T, CC, 256);
    // 2-3. BN(T) in place
    stats(T, 256);
    {
        size_t tot = (size_t)NN * 256;
        hipLaunchKernelGGL(bn_apply_inplace, dim3(2048), blk, 0, stream, T, tot, 256,
                           g1_gamma, g1_beta, mu, rs);
    }
    // 4. AGG = segment_sum(T[src], dst)
    hipMemsetAsync(AGG, 0, (size_t)NN * 256 * sizeof(float), stream);
    hipLaunchKernelGGL(edge_scatter, dim3(EE / 4), blk, 0, stream, src, dst, T, AGG, EE);
    // 5. H = AGG @ w_rel^T + b_rel + T @ w_root^T   [N,512]
    gemm(AGG, w_rel, T, w_root, b_rel, H, 256, 512);
    // 6. Y = H @ w_g2^T + b_g2          [N,192]
    gemm(H, w_g2, nullptr, nullptr, b_g2, Y, 512, CC);
    // 7-8. X2 = BN(Y) + x
    stats(Y, CC);
    {
        size_t tot = (size_t)NN * CC;
        hipLaunchKernelGGL(bn_apply_residual, dim3(2048), blk, 0, stream, Y, x, X2, tot, CC,
                           g2_gamma, g2_beta, mu, rs);
    }
    // ---- FFN ----
    // 9. F = X2 @ w_f1^T + b_f1         [N,512]
    gemm(X2, w_f1, nullptr, nullptr, b_f1, F, CC, 512);
    // 10-11. F = gelu(BN(F))
    stats(F, 512);
    {
        size_t tot = (size_t)NN * 512;
        hipLaunchKernelGGL(bn_apply_gelu_inplace, dim3(2048), blk, 0, stream, F, tot, 512,
                           f1_gamma, f1_beta, mu, rs);
    }
    // 12. F2 = F @ w_f2^T + b_f2        [N,192]
    gemm(F, w_f2, nullptr, nullptr, b_f2, F2, 512, CC);
    // 13-14. out = BN(F2) + X2
    stats(F2, CC);
    {
        size_t tot = (size_t)NN * CC;
        hipLaunchKernelGGL(bn_apply_residual, dim3(2048), blk, 0, stream, F2, X2, out, tot, CC,
                           f2_gamma, f2_beta, mu, rs);
    }
    (void)in_sizes; (void)n_in; (void)out_size; (void)ws_size;
}

// Round 2
// 1512.639 us; speedup vs baseline: 2.6440x; 2.6440x over previous
//
#include <hip/hip_runtime.h>
#include <math.h>

#define NN 50000
#define EE 800000
#define CC 192

// ============ GEMM: out[N,M] = A1@W1^T (+ A2@W2^T) + bias ============
// A row-major [N,K]; W row-major [M,K] (so W^T matmul = NT gemm, both K-contiguous)
__global__ __launch_bounds__(256) void gemm_nt(
    const float* __restrict__ A1, const float* __restrict__ W1,
    const float* __restrict__ A2, const float* __restrict__ W2,
    const float* __restrict__ bias, float* __restrict__ out,
    int Nrows, int K, int M)
{
    __shared__ float As[16][132];
    __shared__ float Bs[16][132];
    const int tid = threadIdx.x;
    const int row0 = blockIdx.y * 128;
    const int col0 = blockIdx.x * 128;
    const int ty = tid / 16, tx = tid % 16;

    float acc[8][8];
#pragma unroll
    for (int i = 0; i < 8; ++i)
#pragma unroll
        for (int j = 0; j < 8; ++j) acc[i][j] = 0.f;

    const int lr = tid >> 2;          // 0..63
    const int lk = (tid & 3) * 4;     // 0,4,8,12

    const int npass = A2 ? 2 : 1;
    for (int pass = 0; pass < npass; ++pass) {
        const float* __restrict__ A = pass ? A2 : A1;
        const float* __restrict__ W = pass ? W2 : W1;
        for (int k0 = 0; k0 < K; k0 += 16) {
#pragma unroll
            for (int h = 0; h < 2; ++h) {
                int r = row0 + lr + h * 64;
                int rc = r < Nrows ? r : Nrows - 1;
                float4 av = *reinterpret_cast<const float4*>(&A[(size_t)rc * K + k0 + lk]);
                As[lk + 0][lr + h * 64] = av.x;
                As[lk + 1][lr + h * 64] = av.y;
                As[lk + 2][lr + h * 64] = av.z;
                As[lk + 3][lr + h * 64] = av.w;
                int n = col0 + lr + h * 64;
                int nc = n < M ? n : M - 1;
                float4 wv = *reinterpret_cast<const float4*>(&W[(size_t)nc * K + k0 + lk]);
                Bs[lk + 0][lr + h * 64] = wv.x;
                Bs[lk + 1][lr + h * 64] = wv.y;
                Bs[lk + 2][lr + h * 64] = wv.z;
                Bs[lk + 3][lr + h * 64] = wv.w;
            }
            __syncthreads();
#pragma unroll
            for (int k = 0; k < 16; ++k) {
                float a[8], b[8];
#pragma unroll
                for (int i = 0; i < 8; ++i) a[i] = As[k][ty * 8 + i];
#pragma unroll
                for (int j = 0; j < 8; ++j) b[j] = Bs[k][tx * 8 + j];
#pragma unroll
                for (int i = 0; i < 8; ++i)
#pragma unroll
                    for (int j = 0; j < 8; ++j) acc[i][j] = fmaf(a[i], b[j], acc[i][j]);
            }
            __syncthreads();
        }
    }

#pragma unroll
    for (int i = 0; i < 8; ++i) {
        int r = row0 + ty * 8 + i;
        if (r >= Nrows) continue;
#pragma unroll
        for (int j = 0; j < 8; ++j) {
            int c = col0 + tx * 8 + j;
            if (c < M) out[(size_t)r * M + c] = acc[i][j] + bias[c];
        }
    }
}

// ============ column stats: sum & sumsq per column (2-stage atomic) ============
__global__ __launch_bounds__(256) void col_stats(
    const float* __restrict__ buf, int Nrows, int M,
    float* __restrict__ sum, float* __restrict__ sumsq)
{
    int col = blockIdx.x * 64 + (threadIdx.x & 63);
    int rg = threadIdx.x >> 6;  // 0..3
    int rows_per_chunk = (Nrows + gridDim.y - 1) / gridDim.y;
    int r0 = blockIdx.y * rows_per_chunk;
    int r1 = min(r0 + rows_per_chunk, Nrows);
    float s = 0.f, q = 0.f;
    for (int r = r0 + rg; r < r1; r += 4) {
        float v = buf[(size_t)r * M + col];
        s += v;
        q += v * v;
    }
    atomicAdd(&sum[col], s);
    atomicAdd(&sumsq[col], q);
}

__global__ void bn_finalize(const float* __restrict__ sum, const float* __restrict__ sumsq,
                            float* __restrict__ mu, float* __restrict__ rs, int M, float invN)
{
    int i = blockIdx.x * blockDim.x + threadIdx.x;
    if (i < M) {
        float m = sum[i] * invN;
        float v = sumsq[i] * invN - m * m;
        mu[i] = m;
        rs[i] = rsqrtf(v + 1e-5f);
    }
}

// ============ BN apply variants ============
__global__ __launch_bounds__(256) void bn_apply_inplace(
    float* __restrict__ buf, size_t total, int M,
    const float* __restrict__ g, const float* __restrict__ b,
    const float* __restrict__ mu, const float* __restrict__ rs)
{
    for (size_t i = (size_t)blockIdx.x * blockDim.x + threadIdx.x; i < total;
         i += (size_t)gridDim.x * blockDim.x) {
        int c = (int)(i % M);
        buf[i] = g[c] * (buf[i] - mu[c]) * rs[c] + b[c];
    }
}

__global__ __launch_bounds__(256) void bn_apply_gelu_inplace(
    float* __restrict__ buf, size_t total, int M,
    const float* __restrict__ g, const float* __restrict__ b,
    const float* __restrict__ mu, const float* __restrict__ rs)
{
    for (size_t i = (size_t)blockIdx.x * blockDim.x + threadIdx.x; i < total;
         i += (size_t)gridDim.x * blockDim.x) {
        int c = (int)(i % M);
        float v = g[c] * (buf[i] - mu[c]) * rs[c] + b[c];
        buf[i] = 0.5f * v * (1.f + erff(v * 0.70710678118654752f));
    }
}

__global__ __launch_bounds__(256) void bn_apply_residual(
    const float* __restrict__ pre, const float* __restrict__ res, float* __restrict__ out,
    size_t total, int M,
    const float* __restrict__ g, const float* __restrict__ b,
    const float* __restrict__ mu, const float* __restrict__ rs)
{
    for (size_t i = (size_t)blockIdx.x * blockDim.x + threadIdx.x; i < total;
         i += (size_t)gridDim.x * blockDim.x) {
        int c = (int)(i % M);
        out[i] = g[c] * (pre[i] - mu[c]) * rs[c] + b[c] + res[i];
    }
}

// ============ CSR build: histogram, scan, fill ============
__global__ __launch_bounds__(256) void hist_count(
    const int* __restrict__ dst, int* __restrict__ cnt, int E)
{
    int e = blockIdx.x * blockDim.x + threadIdx.x;
    if (e < E) atomicAdd(&cnt[dst[e]], 1);
}

__global__ __launch_bounds__(256) void scan_block_sums(
    const int* __restrict__ cnt, int* __restrict__ partials, int n)
{
    __shared__ int sdata[256];
    int i = blockIdx.x * 256 + threadIdx.x;
    sdata[threadIdx.x] = (i < n) ? cnt[i] : 0;
    __syncthreads();
    for (int s = 128; s > 0; s >>= 1) {
        if (threadIdx.x < s) sdata[threadIdx.x] += sdata[threadIdx.x + s];
        __syncthreads();
    }
    if (threadIdx.x == 0) partials[blockIdx.x] = sdata[0];
}

__global__ void scan_partials(int* __restrict__ partials, int nb,
                              int* __restrict__ row_start, int n, int E)
{
    if (blockIdx.x == 0 && threadIdx.x == 0) {
        int acc = 0;
        for (int i = 0; i < nb; ++i) { int t = partials[i]; partials[i] = acc; acc += t; }
        row_start[n] = E;
    }
}

__global__ __launch_bounds__(256) void scan_final(
    const int* __restrict__ cnt, const int* __restrict__ partials,
    int* __restrict__ row_start, int n)
{
    __shared__ int sdata[256];
    int i = blockIdx.x * 256 + threadIdx.x;
    int v = (i < n) ? cnt[i] : 0;
    sdata[threadIdx.x] = v;
    __syncthreads();
    // inclusive Hillis-Steele scan
    for (int s = 1; s < 256; s <<= 1) {
        int t = (threadIdx.x >= s) ? sdata[threadIdx.x - s] : 0;
        __syncthreads();
        sdata[threadIdx.x] += t;
        __syncthreads();
    }
    if (i < n) row_start[i] = partials[blockIdx.x] + sdata[threadIdx.x] - v;
}

__global__ __launch_bounds__(256) void csr_fill(
    const int* __restrict__ src, const int* __restrict__ dst,
    const int* __restrict__ row_start, int* __restrict__ cursor,
    int* __restrict__ srcs_sorted, int E)
{
    int e = blockIdx.x * blockDim.x + threadIdx.x;
    if (e < E) {
        int d = dst[e];
        int pos = row_start[d] + atomicAdd(&cursor[d], 1);
        srcs_sorted[pos] = src[e];
    }
}

// ============ gather-sum: AGG[n] = sum over edges of T[src], 256 ch ============
// one wave per dst node; lane owns 4 contiguous channels
__global__ __launch_bounds__(256) void gather_sum(
    const int* __restrict__ row_start, const int* __restrict__ srcs,
    const float* __restrict__ T, float* __restrict__ AGG, int Nn)
{
    int n = blockIdx.x * 4 + (threadIdx.x >> 6);
    if (n >= Nn) return;
    int c0 = (threadIdx.x & 63) * 4;
    int e0 = row_start[n], e1 = row_start[n + 1];
    float4 acc = make_float4(0.f, 0.f, 0.f, 0.f);
    for (int e = e0; e < e1; ++e) {
        int s = srcs[e];
        float4 v = *reinterpret_cast<const float4*>(&T[(size_t)s * 256 + c0]);
        acc.x += v.x; acc.y += v.y; acc.z += v.z; acc.w += v.w;
    }
    *reinterpret_cast<float4*>(&AGG[(size_t)n * 256 + c0]) = acc;
}

// =====================================================================
extern "C" void kernel_launch(void* const* d_in, const int* in_sizes, int n_in,
                              void* d_out, int out_size, void* d_ws, size_t ws_size,
                              hipStream_t stream)
{
    const float* x        = (const float*)d_in[0];
    const int*   ei       = (const int*)d_in[1];
    const float* w_g1     = (const float*)d_in[2];
    const float* b_g1     = (const float*)d_in[3];
    const float* g1_gamma = (const float*)d_in[4];
    const float* g1_beta  = (const float*)d_in[5];
    const float* w_rel    = (const float*)d_in[6];
    const float* b_rel    = (const float*)d_in[7];
    const float* w_root   = (const float*)d_in[8];
    const float* w_g2     = (const float*)d_in[9];
    const float* b_g2     = (const float*)d_in[10];
    const float* g2_gamma = (const float*)d_in[11];
    const float* g2_beta  = (const float*)d_in[12];
    const float* w_f1     = (const float*)d_in[13];
    const float* b_f1     = (const float*)d_in[14];
    const float* f1_gamma = (const float*)d_in[15];
    const float* f1_beta  = (const float*)d_in[16];
    const float* w_f2     = (const float*)d_in[17];
    const float* b_f2     = (const float*)d_in[18];
    const float* f2_gamma = (const float*)d_in[19];
    const float* f2_beta  = (const float*)d_in[20];

    const int* src = ei;
    const int* dst = ei + EE;

    float* ws  = (float*)d_ws;
    float* T   = ws;                       // [N,256]
    float* AGG = T   + (size_t)NN * 256;   // [N,256]
    float* H   = AGG + (size_t)NN * 256;   // [N,512]
    float* X2  = H   + (size_t)NN * 512;   // [N,192]
    float* S   = X2  + (size_t)NN * 192;   // stats: sum|sumsq|mu|rs, 512 each
    float* sum   = S;
    float* sumsq = S + 512;
    float* mu    = S + 1024;
    float* rs    = S + 1536;
    float* Y  = AGG;  // y2 pre-BN  [N,192]   (AGG dead after step 5)
    float* F  = H;    // ffn hidden [N,512]   (H dead after step 6)
    float* F2 = T;    // f2 pre-BN  [N,192]   (T dead after step 5)

    // CSR scratch lives in H's region (dead until step 5, by which time CSR is done)
    int* row_start   = (int*)H;              // NN+1
    int* cnt         = row_start + NN + 16;  // NN   (cnt and cursor contiguous for one memset)
    int* cursor      = cnt + NN;             // NN
    int* partials    = cursor + NN;          // 256
    int* srcs_sorted = partials + 256;       // EE

    float* out = (float*)d_out;
    const float invN = 1.f / (float)NN;
    dim3 blk(256);
    const int GY = (NN + 127) / 128;
    const int NB_SCAN = (NN + 255) / 256;    // 196

    auto gemm = [&](const float* A1, const float* W1, const float* A2, const float* W2,
                    const float* bias, float* o, int K, int M) {
        dim3 grid((M + 127) / 128, GY);
        hipLaunchKernelGGL(gemm_nt, grid, blk, 0, stream, A1, W1, A2, W2, bias, o, NN, K, M);
    };
    auto stats = [&](const float* buf, int M) {
        hipMemsetAsync(sum, 0, 1024 * sizeof(float), stream);  // sum+sumsq
        dim3 grid(M / 64, 196);
        hipLaunchKernelGGL(col_stats, grid, blk, 0, stream, buf, NN, M, sum, sumsq);
        hipLaunchKernelGGL(bn_finalize, dim3(2), dim3(256), 0, stream, sum, sumsq, mu, rs, M, invN);
    };

    // ---- Grapher ----
    // 1. T = x @ w_g1^T + b_g1          [N,256]
    gemm(x, w_g1, nullptr, nullptr, b_g1, T, CC, 256);
    // 2-3. BN(T) in place
    stats(T, 256);
    {
        size_t tot = (size_t)NN * 256;
        hipLaunchKernelGGL(bn_apply_inplace, dim3(2048), blk, 0, stream, T, tot, 256,
                           g1_gamma, g1_beta, mu, rs);
    }
    // 4. AGG = segment_sum(T[src], dst)   — CSR build + gather-sum (no float atomics)
    hipMemsetAsync(cnt, 0, 2 * NN * sizeof(int), stream);  // cnt + cursor
    hipLaunchKernelGGL(hist_count, dim3((EE + 255) / 256), blk, 0, stream, dst, cnt, EE);
    hipLaunchKernelGGL(scan_block_sums, dim3(NB_SCAN), blk, 0, stream, cnt, partials, NN);
    hipLaunchKernelGGL(scan_partials, dim3(1), dim3(64), 0, stream, partials, NB_SCAN,
                       row_start, NN, EE);
    hipLaunchKernelGGL(scan_final, dim3(NB_SCAN), blk, 0, stream, cnt, partials, row_start, NN);
    hipLaunchKernelGGL(csr_fill, dim3((EE + 255) / 256), blk, 0, stream, src, dst,
                       row_start, cursor, srcs_sorted, EE);
    hipLaunchKernelGGL(gather_sum, dim3((NN + 3) / 4), blk, 0, stream,
                       row_start, srcs_sorted, T, AGG, NN);
    // 5. H = AGG @ w_rel^T + b_rel + T @ w_root^T   [N,512]
    gemm(AGG, w_rel, T, w_root, b_rel, H, 256, 512);
    // 6. Y = H @ w_g2^T + b_g2          [N,192]
    gemm(H, w_g2, nullptr, nullptr, b_g2, Y, 512, CC);
    // 7-8. X2 = BN(Y) + x
    stats(Y, CC);
    {
        size_t tot = (size_t)NN * CC;
        hipLaunchKernelGGL(bn_apply_residual, dim3(2048), blk, 0, stream, Y, x, X2, tot, CC,
                           g2_gamma, g2_beta, mu, rs);
    }
    // ---- FFN ----
    // 9. F = X2 @ w_f1^T + b_f1         [N,512]
    gemm(X2, w_f1, nullptr, nullptr, b_f1, F, CC, 512);
    // 10-11. F = gelu(BN(F))
    stats(F, 512);
    {
        size_t tot = (size_t)NN * 512;
        hipLaunchKernelGGL(bn_apply_gelu_inplace, dim3(2048), blk, 0, stream, F, tot, 512,
                           f1_gamma, f1_beta, mu, rs);
    }
    // 12. F2 = F @ w_f2^T + b_f2        [N,192]
    gemm(F, w_f2, nullptr, nullptr, b_f2, F2, 512, CC);
    // 13-14. out = BN(F2) + X2
    stats(F2, CC);
    {
        size_t tot = (size_t)NN * CC;
        hipLaunchKernelGGL(bn_apply_residual, dim3(2048), blk, 0, stream, F2, X2, out, tot, CC,
                           f2_gamma, f2_beta, mu, rs);
    }
    (void)in_sizes; (void)n_in; (void)out_size; (void)ws_size;
}

// Round 3
// 673.035 us; speedup vs baseline: 5.9423x; 2.2475x over previous
//
#include <hip/hip_runtime.h>
#include <hip/hip_bf16.h>
#include <math.h>

#define NN 50000
#define EE 800000
#define CC 192

typedef __attribute__((ext_vector_type(4))) float f32x4;
typedef __attribute__((ext_vector_type(8))) short bfx8;

static __device__ __forceinline__ unsigned short f2bf(float f) {
    return __builtin_bit_cast(unsigned short, __float2bfloat16(f));
}
static __device__ __forceinline__ float b2f(unsigned short u) {
    unsigned v = ((unsigned)u) << 16;
    return __builtin_bit_cast(float, v);
}

// ============ bf16 MFMA GEMM: out[N,M] = A1@W1^T (+ A2@W2^T) + bias ============
// A row-major [N,K] (bf16, or fp32 converted in staging); W row-major [M,K] bf16.
// 128x128 tile, BK=32, 4 waves 2x2, 64x64 per wave, 16x16x32 MFMA.
#define BM 128
#define BKD 32
#define SA 40  // padded LDS row stride (shorts): 32 data + 8 pad

template <bool A_F32, bool OUT_BF16, bool DUAL>
__global__ __launch_bounds__(256) void gemm_mfma(
    const void* __restrict__ A1v, const unsigned short* __restrict__ W1,
    const void* __restrict__ A2v, const unsigned short* __restrict__ W2,
    const float* __restrict__ bias, void* __restrict__ outv,
    int Nrows, int K, int M)
{
    __shared__ short lds[2][2][BM * SA];
    const int tid  = threadIdx.x;
    const int lane = tid & 63;
    const int wave = tid >> 6;
    const int wm = wave >> 1, wn = wave & 1;
    const int row0 = blockIdx.y * BM;
    const int col0 = blockIdx.x * BM;

    const int nk = K / BKD;
    const int ntot = DUAL ? 2 * nk : nk;

    const int ar = tid >> 2;          // 0..63 (and +64)
    const int ko = (tid & 3) * 8;

    f32x4 acc[4][4];
#pragma unroll
    for (int i = 0; i < 4; ++i)
#pragma unroll
        for (int j = 0; j < 4; ++j) acc[i][j] = f32x4{0.f, 0.f, 0.f, 0.f};

    const int r0c = min(row0 + ar, Nrows - 1);
    const int r1c = min(row0 + ar + 64, Nrows - 1);
    const int c0c = min(col0 + ar, M - 1);
    const int c1c = min(col0 + ar + 64, M - 1);

    auto load_step = [&](int t, bfx8& a0, bfx8& a1, bfx8& b0, bfx8& b1) {
        int p = (DUAL && t >= nk) ? 1 : 0;
        int k0 = (t - p * nk) * BKD;
        const unsigned short* W = p ? W2 : W1;
        if (A_F32) {
            const float* A = (const float*)(p ? A2v : A1v);
            const float* pa0 = &A[(size_t)r0c * K + k0 + ko];
            const float* pa1 = &A[(size_t)r1c * K + k0 + ko];
            float4 u0 = *(const float4*)pa0, u1 = *(const float4*)(pa0 + 4);
            float4 v0 = *(const float4*)pa1, v1 = *(const float4*)(pa1 + 4);
            a0 = bfx8{(short)f2bf(u0.x), (short)f2bf(u0.y), (short)f2bf(u0.z), (short)f2bf(u0.w),
                      (short)f2bf(u1.x), (short)f2bf(u1.y), (short)f2bf(u1.z), (short)f2bf(u1.w)};
            a1 = bfx8{(short)f2bf(v0.x), (short)f2bf(v0.y), (short)f2bf(v0.z), (short)f2bf(v0.w),
                      (short)f2bf(v1.x), (short)f2bf(v1.y), (short)f2bf(v1.z), (short)f2bf(v1.w)};
        } else {
            const unsigned short* A = (const unsigned short*)(p ? A2v : A1v);
            a0 = *(const bfx8*)&A[(size_t)r0c * K + k0 + ko];
            a1 = *(const bfx8*)&A[(size_t)r1c * K + k0 + ko];
        }
        b0 = *(const bfx8*)&W[(size_t)c0c * K + k0 + ko];
        b1 = *(const bfx8*)&W[(size_t)c1c * K + k0 + ko];
    };
    auto write_step = [&](int buf, bfx8 a0, bfx8 a1, bfx8 b0, bfx8 b1) {
        *(bfx8*)&lds[buf][0][ar * SA + ko] = a0;
        *(bfx8*)&lds[buf][0][(ar + 64) * SA + ko] = a1;
        *(bfx8*)&lds[buf][1][ar * SA + ko] = b0;
        *(bfx8*)&lds[buf][1][(ar + 64) * SA + ko] = b1;
    };
    auto compute = [&](int buf) {
        const short* Al = lds[buf][0];
        const short* Bl = lds[buf][1];
        bfx8 af[4], bfr[4];
        const int rbase = wm * 64 + (lane & 15);
        const int cbase = wn * 64 + (lane & 15);
        const int kroff = (lane >> 4) * 8;
#pragma unroll
        for (int i = 0; i < 4; ++i) af[i]  = *(const bfx8*)&Al[(rbase + i * 16) * SA + kroff];
#pragma unroll
        for (int j = 0; j < 4; ++j) bfr[j] = *(const bfx8*)&Bl[(cbase + j * 16) * SA + kroff];
#pragma unroll
        for (int i = 0; i < 4; ++i)
#pragma unroll
            for (int j = 0; j < 4; ++j)
                acc[i][j] = __builtin_amdgcn_mfma_f32_16x16x32_bf16(af[i], bfr[j], acc[i][j], 0, 0, 0);
    };

    bfx8 a0, a1, b0, b1;
    load_step(0, a0, a1, b0, b1);
    write_step(0, a0, a1, b0, b1);
    for (int t = 0; t < ntot; ++t) {
        const bool more = (t + 1 < ntot);
        if (more) load_step(t + 1, a0, a1, b0, b1);
        __syncthreads();
        compute(t & 1);
        if (more) write_step((t + 1) & 1, a0, a1, b0, b1);
    }

    // epilogue
#pragma unroll
    for (int i = 0; i < 4; ++i) {
        const int rb = row0 + wm * 64 + i * 16 + (lane >> 4) * 4;
#pragma unroll
        for (int j = 0; j < 4; ++j) {
            const int c = col0 + wn * 64 + j * 16 + (lane & 15);
            if (c >= M) continue;
            const float bv = bias[c];
#pragma unroll
            for (int r = 0; r < 4; ++r) {
                const int rr = rb + r;
                if (rr >= Nrows) continue;
                const float val = acc[i][j][r] + bv;
                if (OUT_BF16) ((unsigned short*)outv)[(size_t)rr * M + c] = f2bf(val);
                else          ((float*)outv)[(size_t)rr * M + c] = val;
            }
        }
    }
}

// ============ weight conversion fp32 -> bf16 arena ============
#define W_G1 0
#define W_REL 49152
#define W_ROOT 180224
#define W_G2 311296
#define W_F1 409600
#define W_F2 507904
#define W_TOT 606208

__global__ __launch_bounds__(256) void convert_weights(
    const float* __restrict__ w0, const float* __restrict__ w1, const float* __restrict__ w2,
    const float* __restrict__ w3, const float* __restrict__ w4, const float* __restrict__ w5,
    unsigned short* __restrict__ out)
{
    int i = blockIdx.x * 256 + threadIdx.x;
    if (i >= W_TOT) return;
    const float* src; int off;
    if      (i < W_REL)  { src = w0; off = W_G1; }
    else if (i < W_ROOT) { src = w1; off = W_REL; }
    else if (i < W_G2)   { src = w2; off = W_ROOT; }
    else if (i < W_F1)   { src = w3; off = W_G2; }
    else if (i < W_F2)   { src = w4; off = W_F1; }
    else                 { src = w5; off = W_F2; }
    out[i] = f2bf(src[i - off]);
}

// ============ column stats: sum & sumsq per column ============
__global__ __launch_bounds__(256) void col_stats(
    const float* __restrict__ buf, int Nrows, int M,
    float* __restrict__ sum, float* __restrict__ sumsq)
{
    int col = blockIdx.x * 64 + (threadIdx.x & 63);
    int rg = threadIdx.x >> 6;
    int rows_per_chunk = (Nrows + gridDim.y - 1) / gridDim.y;
    int r0 = blockIdx.y * rows_per_chunk;
    int r1 = min(r0 + rows_per_chunk, Nrows);
    float s = 0.f, q = 0.f;
    for (int r = r0 + rg; r < r1; r += 4) {
        float v = buf[(size_t)r * M + col];
        s += v;
        q += v * v;
    }
    atomicAdd(&sum[col], s);
    atomicAdd(&sumsq[col], q);
}

__global__ void bn_finalize(const float* __restrict__ sum, const float* __restrict__ sumsq,
                            float* __restrict__ mu, float* __restrict__ rs, int M, float invN)
{
    int i = blockIdx.x * blockDim.x + threadIdx.x;
    if (i < M) {
        float m = sum[i] * invN;
        float v = sumsq[i] * invN - m * m;
        mu[i] = m;
        rs[i] = rsqrtf(v + 1e-5f);
    }
}

// ============ BN apply variants (vectorized x4) ============
__global__ __launch_bounds__(256) void bn_apply_bf16(
    const float* __restrict__ pre, unsigned short* __restrict__ outb,
    int total4, int M4, const float* __restrict__ g, const float* __restrict__ b,
    const float* __restrict__ mu, const float* __restrict__ rs)
{
    for (int i = blockIdx.x * 256 + threadIdx.x; i < total4; i += gridDim.x * 256) {
        int c = (i % M4) * 4;
        float4 v = *(const float4*)&pre[(size_t)i * 4];
        float4 gv = *(const float4*)&g[c];
        float4 bv = *(const float4*)&b[c];
        float4 mv = *(const float4*)&mu[c];
        float4 rv = *(const float4*)&rs[c];
        ushort4 o;
        o.x = f2bf(gv.x * (v.x - mv.x) * rv.x + bv.x);
        o.y = f2bf(gv.y * (v.y - mv.y) * rv.y + bv.y);
        o.z = f2bf(gv.z * (v.z - mv.z) * rv.z + bv.z);
        o.w = f2bf(gv.w * (v.w - mv.w) * rv.w + bv.w);
        *(ushort4*)&outb[(size_t)i * 4] = o;
    }
}

__global__ __launch_bounds__(256) void bn_apply_gelu_bf16(
    const float* __restrict__ pre, unsigned short* __restrict__ outb,
    int total4, int M4, const float* __restrict__ g, const float* __restrict__ b,
    const float* __restrict__ mu, const float* __restrict__ rs)
{
    for (int i = blockIdx.x * 256 + threadIdx.x; i < total4; i += gridDim.x * 256) {
        int c = (i % M4) * 4;
        float4 v = *(const float4*)&pre[(size_t)i * 4];
        float4 gv = *(const float4*)&g[c];
        float4 bv = *(const float4*)&b[c];
        float4 mv = *(const float4*)&mu[c];
        float4 rv = *(const float4*)&rs[c];
        float t0 = gv.x * (v.x - mv.x) * rv.x + bv.x;
        float t1 = gv.y * (v.y - mv.y) * rv.y + bv.y;
        float t2 = gv.z * (v.z - mv.z) * rv.z + bv.z;
        float t3 = gv.w * (v.w - mv.w) * rv.w + bv.w;
        const float k = 0.70710678118654752f;
        ushort4 o;
        o.x = f2bf(0.5f * t0 * (1.f + erff(t0 * k)));
        o.y = f2bf(0.5f * t1 * (1.f + erff(t1 * k)));
        o.z = f2bf(0.5f * t2 * (1.f + erff(t2 * k)));
        o.w = f2bf(0.5f * t3 * (1.f + erff(t3 * k)));
        *(ushort4*)&outb[(size_t)i * 4] = o;
    }
}

__global__ __launch_bounds__(256) void bn_apply_res_bf16(
    const float* __restrict__ pre, const float* __restrict__ res,
    unsigned short* __restrict__ outb,
    int total4, int M4, const float* __restrict__ g, const float* __restrict__ b,
    const float* __restrict__ mu, const float* __restrict__ rs)
{
    for (int i = blockIdx.x * 256 + threadIdx.x; i < total4; i += gridDim.x * 256) {
        int c = (i % M4) * 4;
        float4 v = *(const float4*)&pre[(size_t)i * 4];
        float4 x = *(const float4*)&res[(size_t)i * 4];
        float4 gv = *(const float4*)&g[c];
        float4 bv = *(const float4*)&b[c];
        float4 mv = *(const float4*)&mu[c];
        float4 rv = *(const float4*)&rs[c];
        ushort4 o;
        o.x = f2bf(gv.x * (v.x - mv.x) * rv.x + bv.x + x.x);
        o.y = f2bf(gv.y * (v.y - mv.y) * rv.y + bv.y + x.y);
        o.z = f2bf(gv.z * (v.z - mv.z) * rv.z + bv.z + x.z);
        o.w = f2bf(gv.w * (v.w - mv.w) * rv.w + bv.w + x.w);
        *(ushort4*)&outb[(size_t)i * 4] = o;
    }
}

__global__ __launch_bounds__(256) void bn_apply_res_out(
    const float* __restrict__ pre, const unsigned short* __restrict__ resb,
    float* __restrict__ out,
    int total4, int M4, const float* __restrict__ g, const float* __restrict__ b,
    const float* __restrict__ mu, const float* __restrict__ rs)
{
    for (int i = blockIdx.x * 256 + threadIdx.x; i < total4; i += gridDim.x * 256) {
        int c = (i % M4) * 4;
        float4 v = *(const float4*)&pre[(size_t)i * 4];
        ushort4 x = *(const ushort4*)&resb[(size_t)i * 4];
        float4 gv = *(const float4*)&g[c];
        float4 bv = *(const float4*)&b[c];
        float4 mv = *(const float4*)&mu[c];
        float4 rv = *(const float4*)&rs[c];
        float4 o;
        o.x = gv.x * (v.x - mv.x) * rv.x + bv.x + b2f(x.x);
        o.y = gv.y * (v.y - mv.y) * rv.y + bv.y + b2f(x.y);
        o.z = gv.z * (v.z - mv.z) * rv.z + bv.z + b2f(x.z);
        o.w = gv.w * (v.w - mv.w) * rv.w + bv.w + b2f(x.w);
        *(float4*)&out[(size_t)i * 4] = o;
    }
}

// ============ CSR build: histogram, scan, fill ============
__global__ __launch_bounds__(256) void hist_count(
    const int* __restrict__ dst, int* __restrict__ cnt, int E)
{
    int e = blockIdx.x * blockDim.x + threadIdx.x;
    if (e < E) atomicAdd(&cnt[dst[e]], 1);
}

__global__ __launch_bounds__(256) void scan_block_sums(
    const int* __restrict__ cnt, int* __restrict__ partials, int n)
{
    __shared__ int sdata[256];
    int i = blockIdx.x * 256 + threadIdx.x;
    sdata[threadIdx.x] = (i < n) ? cnt[i] : 0;
    __syncthreads();
    for (int s = 128; s > 0; s >>= 1) {
        if (threadIdx.x < s) sdata[threadIdx.x] += sdata[threadIdx.x + s];
        __syncthreads();
    }
    if (threadIdx.x == 0) partials[blockIdx.x] = sdata[0];
}

__global__ void scan_partials(int* __restrict__ partials, int nb,
                              int* __restrict__ row_start, int n, int E)
{
    if (blockIdx.x == 0 && threadIdx.x == 0) {
        int acc = 0;
        for (int i = 0; i < nb; ++i) { int t = partials[i]; partials[i] = acc; acc += t; }
        row_start[n] = E;
    }
}

__global__ __launch_bounds__(256) void scan_final(
    const int* __restrict__ cnt, const int* __restrict__ partials,
    int* __restrict__ row_start, int n)
{
    __shared__ int sdata[256];
    int i = blockIdx.x * 256 + threadIdx.x;
    int v = (i < n) ? cnt[i] : 0;
    sdata[threadIdx.x] = v;
    __syncthreads();
    for (int s = 1; s < 256; s <<= 1) {
        int t = (threadIdx.x >= s) ? sdata[threadIdx.x - s] : 0;
        __syncthreads();
        sdata[threadIdx.x] += t;
        __syncthreads();
    }
    if (i < n) row_start[i] = partials[blockIdx.x] + sdata[threadIdx.x] - v;
}

__global__ __launch_bounds__(256) void csr_fill(
    const int* __restrict__ src, const int* __restrict__ dst,
    const int* __restrict__ row_start, int* __restrict__ cursor,
    int* __restrict__ srcs_sorted, int E)
{
    int e = blockIdx.x * blockDim.x + threadIdx.x;
    if (e < E) {
        int d = dst[e];
        int pos = row_start[d] + atomicAdd(&cursor[d], 1);
        srcs_sorted[pos] = src[e];
    }
}

// ============ gather-sum (bf16 in/out): AGG[n] = sum T[src], 256 ch ============
__global__ __launch_bounds__(256) void gather_sum(
    const int* __restrict__ row_start, const int* __restrict__ srcs,
    const unsigned short* __restrict__ T, unsigned short* __restrict__ AGG, int Nn)
{
    int n = blockIdx.x * 4 + (threadIdx.x >> 6);
    if (n >= Nn) return;
    int c0 = (threadIdx.x & 63) * 4;
    int e0 = row_start[n], e1 = row_start[n + 1];
    float ax = 0.f, ay = 0.f, az = 0.f, aw = 0.f;
    for (int e = e0; e < e1; ++e) {
        int s = srcs[e];
        ushort4 v = *(const ushort4*)&T[(size_t)s * 256 + c0];
        ax += b2f(v.x); ay += b2f(v.y); az += b2f(v.z); aw += b2f(v.w);
    }
    ushort4 o = {f2bf(ax), f2bf(ay), f2bf(az), f2bf(aw)};
    *(ushort4*)&AGG[(size_t)n * 256 + c0] = o;
}

// =====================================================================
extern "C" void kernel_launch(void* const* d_in, const int* in_sizes, int n_in,
                              void* d_out, int out_size, void* d_ws, size_t ws_size,
                              hipStream_t stream)
{
    const float* x        = (const float*)d_in[0];
    const int*   ei       = (const int*)d_in[1];
    const float* w_g1     = (const float*)d_in[2];
    const float* b_g1     = (const float*)d_in[3];
    const float* g1_gamma = (const float*)d_in[4];
    const float* g1_beta  = (const float*)d_in[5];
    const float* w_rel    = (const float*)d_in[6];
    const float* b_rel    = (const float*)d_in[7];
    const float* w_root   = (const float*)d_in[8];
    const float* w_g2     = (const float*)d_in[9];
    const float* b_g2     = (const float*)d_in[10];
    const float* g2_gamma = (const float*)d_in[11];
    const float* g2_beta  = (const float*)d_in[12];
    const float* w_f1     = (const float*)d_in[13];
    const float* b_f1     = (const float*)d_in[14];
    const float* f1_gamma = (const float*)d_in[15];
    const float* f1_beta  = (const float*)d_in[16];
    const float* w_f2     = (const float*)d_in[17];
    const float* b_f2     = (const float*)d_in[18];
    const float* f2_gamma = (const float*)d_in[19];
    const float* f2_beta  = (const float*)d_in[20];

    const int* src = ei;
    const int* dst = ei + EE;

    // workspace layout (~206 MB)
    char* p = (char*)d_ws;
    float* Pre = (float*)p;                     p += (size_t)NN * 512 * 4;  // shared fp32 pre-BN
    unsigned short* R2 = (unsigned short*)p;    p += (size_t)NN * 512 * 2;  // Hb then Fb
    unsigned short* R3 = (unsigned short*)p;    p += (size_t)NN * 256 * 2;  // Tb then X2b
    unsigned short* R4 = (unsigned short*)p;    p += (size_t)NN * 256 * 2;  // AGGb
    unsigned short* Wb = (unsigned short*)p;    p += 2 * 1024 * 1024;       // bf16 weights
    float* sum   = (float*)p;
    float* sumsq = sum + 512;
    float* mu    = sum + 1024;
    float* rs    = sum + 1536;

    unsigned short* Tb   = R3;
    unsigned short* AGGb = R4;
    unsigned short* Hb   = R2;
    unsigned short* X2b  = R3;
    unsigned short* Fb   = R2;

    // CSR scratch in Pre region (dead between BN-apply(T) and GEMM3)
    int* row_start   = (int*)Pre;            // NN+1
    int* cnt         = row_start + NN + 16;
    int* cursor      = cnt + NN;
    int* partials    = cursor + NN;
    int* srcs_sorted = partials + 256;       // EE

    float* out = (float*)d_out;
    const float invN = 1.f / (float)NN;
    dim3 blk(256);
    const int GY = (NN + 127) / 128;         // 391
    const int NB_SCAN = (NN + 255) / 256;    // 196

    auto stats = [&](const float* buf, int M) {
        hipMemsetAsync(sum, 0, 1024 * sizeof(float), stream);
        dim3 grid(M / 64, 196);
        hipLaunchKernelGGL(col_stats, grid, blk, 0, stream, buf, NN, M, sum, sumsq);
        hipLaunchKernelGGL(bn_finalize, dim3(2), dim3(256), 0, stream, sum, sumsq, mu, rs, M, invN);
    };

    // 0. weights -> bf16 arena
    hipLaunchKernelGGL(convert_weights, dim3((W_TOT + 255) / 256), blk, 0, stream,
                       w_g1, w_rel, w_root, w_g2, w_f1, w_f2, Wb);

    // ---- Grapher ----
    // 1. Pre = x @ w_g1^T + b_g1   [N,256]   (A fp32 converted in staging)
    hipLaunchKernelGGL((gemm_mfma<true, false, false>), dim3(2, GY), blk, 0, stream,
                       (const void*)x, Wb + W_G1, nullptr, nullptr, b_g1, (void*)Pre, NN, CC, 256);
    // 2-3. Tb = bf16(BN(Pre))
    stats(Pre, 256);
    hipLaunchKernelGGL(bn_apply_bf16, dim3(2048), blk, 0, stream, Pre, Tb,
                       NN * 64, 64, g1_gamma, g1_beta, mu, rs);
    // 4. CSR build + gather (AGGb = segsum(Tb[src]))
    hipMemsetAsync(cnt, 0, 2 * NN * sizeof(int), stream);
    hipLaunchKernelGGL(hist_count, dim3((EE + 255) / 256), blk, 0, stream, dst, cnt, EE);
    hipLaunchKernelGGL(scan_block_sums, dim3(NB_SCAN), blk, 0, stream, cnt, partials, NN);
    hipLaunchKernelGGL(scan_partials, dim3(1), dim3(64), 0, stream, partials, NB_SCAN,
                       row_start, NN, EE);
    hipLaunchKernelGGL(scan_final, dim3(NB_SCAN), blk, 0, stream, cnt, partials, row_start, NN);
    hipLaunchKernelGGL(csr_fill, dim3((EE + 255) / 256), blk, 0, stream, src, dst,
                       row_start, cursor, srcs_sorted, EE);
    hipLaunchKernelGGL(gather_sum, dim3((NN + 3) / 4), blk, 0, stream,
                       row_start, srcs_sorted, Tb, AGGb, NN);
    // 5. Hb = bf16(AGGb @ w_rel^T + b_rel + Tb @ w_root^T)   [N,512]
    hipLaunchKernelGGL((gemm_mfma<false, true, true>), dim3(4, GY), blk, 0, stream,
                       (const void*)AGGb, Wb + W_REL, (const void*)Tb, Wb + W_ROOT,
                       b_rel, (void*)Hb, NN, 256, 512);
    // 6. Pre = Hb @ w_g2^T + b_g2   [N,192]
    hipLaunchKernelGGL((gemm_mfma<false, false, false>), dim3(2, GY), blk, 0, stream,
                       (const void*)Hb, Wb + W_G2, nullptr, nullptr, b_g2, (void*)Pre, NN, 512, CC);
    // 7-8. X2b = bf16(BN(Pre) + x)
    stats(Pre, CC);
    hipLaunchKernelGGL(bn_apply_res_bf16, dim3(2048), blk, 0, stream, Pre, x, X2b,
                       NN * 48, 48, g2_gamma, g2_beta, mu, rs);
    // ---- FFN ----
    // 9. Pre = X2b @ w_f1^T + b_f1   [N,512]
    hipLaunchKernelGGL((gemm_mfma<false, false, false>), dim3(4, GY), blk, 0, stream,
                       (const void*)X2b, Wb + W_F1, nullptr, nullptr, b_f1, (void*)Pre, NN, CC, 512);
    // 10-11. Fb = bf16(gelu(BN(Pre)))
    stats(Pre, 512);
    hipLaunchKernelGGL(bn_apply_gelu_bf16, dim3(2048), blk, 0, stream, Pre, Fb,
                       NN * 128, 128, f1_gamma, f1_beta, mu, rs);
    // 12. Pre = Fb @ w_f2^T + b_f2   [N,192]
    hipLaunchKernelGGL((gemm_mfma<false, false, false>), dim3(2, GY), blk, 0, stream,
                       (const void*)Fb, Wb + W_F2, nullptr, nullptr, b_f2, (void*)Pre, NN, 512, CC);
    // 13-14. out = BN(Pre) + X2b
    stats(Pre, CC);
    hipLaunchKernelGGL(bn_apply_res_out, dim3(2048), blk, 0, stream, Pre, X2b, out,
                       NN * 48, 48, f2_gamma, f2_beta, mu, rs);

    (void)in_sizes; (void)n_in; (void)out_size; (void)ws_size;
}

// Round 4
// 537.417 us; speedup vs baseline: 7.4418x; 1.2524x over previous
//
#include <hip/hip_runtime.h>
#include <hip/hip_bf16.h>
#include <math.h>

#define NN 50000
#define EE 800000
#define CC 192

typedef __attribute__((ext_vector_type(4))) float f32x4;
typedef __attribute__((ext_vector_type(8))) short bfx8;
typedef __attribute__((ext_vector_type(8))) unsigned short u16x8;

static __device__ __forceinline__ unsigned short f2bf(float f) {
    return __builtin_bit_cast(unsigned short, __float2bfloat16(f));
}
static __device__ __forceinline__ float b2f(unsigned short u) {
    unsigned v = ((unsigned)u) << 16;
    return __builtin_bit_cast(float, v);
}

// ============ bf16 MFMA GEMM: out[N,M] = A1@W1^T (+ A2@W2^T) + bias ============
// A row-major [N,K] (bf16, or fp32 converted in staging); W row-major [M,K] bf16.
// 128x128 tile, BK=32, 4 waves 2x2, 64x64 per wave, 16x16x32 MFMA.
// STATS: fused BN column sum/sumsq reduction (LDS atomics -> global atomics).
#define BM 128
#define BKD 32
#define SA 40  // padded LDS row stride (shorts): 32 data + 8 pad

template <bool A_F32, bool OUT_BF16, bool DUAL, bool STATS>
__global__ __launch_bounds__(256) void gemm_mfma(
    const void* __restrict__ A1v, const unsigned short* __restrict__ W1,
    const void* __restrict__ A2v, const unsigned short* __restrict__ W2,
    const float* __restrict__ bias, void* __restrict__ outv,
    float* __restrict__ gsum, float* __restrict__ gsq,
    int Nrows, int K, int M)
{
    __shared__ short lds[2][2][BM * SA];
    __shared__ float s_sum[BM], s_sq[BM];
    const int tid  = threadIdx.x;
    const int lane = tid & 63;
    const int wave = tid >> 6;
    const int wm = wave >> 1, wn = wave & 1;
    const int row0 = blockIdx.y * BM;
    const int col0 = blockIdx.x * BM;

    const int nk = K / BKD;
    const int ntot = DUAL ? 2 * nk : nk;

    const int ar = tid >> 2;          // 0..63 (and +64)
    const int ko = (tid & 3) * 8;

    f32x4 acc[4][4];
#pragma unroll
    for (int i = 0; i < 4; ++i)
#pragma unroll
        for (int j = 0; j < 4; ++j) acc[i][j] = f32x4{0.f, 0.f, 0.f, 0.f};

    const int r0c = min(row0 + ar, Nrows - 1);
    const int r1c = min(row0 + ar + 64, Nrows - 1);
    const int c0c = min(col0 + ar, M - 1);
    const int c1c = min(col0 + ar + 64, M - 1);

    auto load_step = [&](int t, bfx8& a0, bfx8& a1, bfx8& b0, bfx8& b1) {
        int p = (DUAL && t >= nk) ? 1 : 0;
        int k0 = (t - p * nk) * BKD;
        const unsigned short* W = p ? W2 : W1;
        if (A_F32) {
            const float* A = (const float*)(p ? A2v : A1v);
            const float* pa0 = &A[(size_t)r0c * K + k0 + ko];
            const float* pa1 = &A[(size_t)r1c * K + k0 + ko];
            float4 u0 = *(const float4*)pa0, u1 = *(const float4*)(pa0 + 4);
            float4 v0 = *(const float4*)pa1, v1 = *(const float4*)(pa1 + 4);
            a0 = bfx8{(short)f2bf(u0.x), (short)f2bf(u0.y), (short)f2bf(u0.z), (short)f2bf(u0.w),
                      (short)f2bf(u1.x), (short)f2bf(u1.y), (short)f2bf(u1.z), (short)f2bf(u1.w)};
            a1 = bfx8{(short)f2bf(v0.x), (short)f2bf(v0.y), (short)f2bf(v0.z), (short)f2bf(v0.w),
                      (short)f2bf(v1.x), (short)f2bf(v1.y), (short)f2bf(v1.z), (short)f2bf(v1.w)};
        } else {
            const unsigned short* A = (const unsigned short*)(p ? A2v : A1v);
            a0 = *(const bfx8*)&A[(size_t)r0c * K + k0 + ko];
            a1 = *(const bfx8*)&A[(size_t)r1c * K + k0 + ko];
        }
        b0 = *(const bfx8*)&W[(size_t)c0c * K + k0 + ko];
        b1 = *(const bfx8*)&W[(size_t)c1c * K + k0 + ko];
    };
    auto write_step = [&](int buf, bfx8 a0, bfx8 a1, bfx8 b0, bfx8 b1) {
        *(bfx8*)&lds[buf][0][ar * SA + ko] = a0;
        *(bfx8*)&lds[buf][0][(ar + 64) * SA + ko] = a1;
        *(bfx8*)&lds[buf][1][ar * SA + ko] = b0;
        *(bfx8*)&lds[buf][1][(ar + 64) * SA + ko] = b1;
    };
    auto compute = [&](int buf) {
        const short* Al = lds[buf][0];
        const short* Bl = lds[buf][1];
        bfx8 af[4], bfr[4];
        const int rbase = wm * 64 + (lane & 15);
        const int cbase = wn * 64 + (lane & 15);
        const int kroff = (lane >> 4) * 8;
#pragma unroll
        for (int i = 0; i < 4; ++i) af[i]  = *(const bfx8*)&Al[(rbase + i * 16) * SA + kroff];
#pragma unroll
        for (int j = 0; j < 4; ++j) bfr[j] = *(const bfx8*)&Bl[(cbase + j * 16) * SA + kroff];
#pragma unroll
        for (int i = 0; i < 4; ++i)
#pragma unroll
            for (int j = 0; j < 4; ++j)
                acc[i][j] = __builtin_amdgcn_mfma_f32_16x16x32_bf16(af[i], bfr[j], acc[i][j], 0, 0, 0);
    };

    bfx8 a0, a1, b0, b1;
    load_step(0, a0, a1, b0, b1);
    write_step(0, a0, a1, b0, b1);
    for (int t = 0; t < ntot; ++t) {
        const bool more = (t + 1 < ntot);
        if (more) load_step(t + 1, a0, a1, b0, b1);
        __syncthreads();
        compute(t & 1);
        if (more) write_step((t + 1) & 1, a0, a1, b0, b1);
    }

    // ---- epilogue (+ optional fused column stats) ----
    if (STATS) {
        if (tid < BM) { s_sum[tid] = 0.f; s_sq[tid] = 0.f; }
        __syncthreads();
    }
#pragma unroll
    for (int j = 0; j < 4; ++j) {
        const int cl = wn * 64 + j * 16 + (lane & 15);
        const int c = col0 + cl;
        if (c >= M) continue;
        const float bv = bias[c];
        float cs = 0.f, cq = 0.f;
#pragma unroll
        for (int i = 0; i < 4; ++i) {
            const int rb = row0 + wm * 64 + i * 16 + (lane >> 4) * 4;
#pragma unroll
            for (int r = 0; r < 4; ++r) {
                const int rr = rb + r;
                if (rr >= Nrows) continue;
                const float val = acc[i][j][r] + bv;
                if (OUT_BF16) ((unsigned short*)outv)[(size_t)rr * M + c] = f2bf(val);
                else          ((float*)outv)[(size_t)rr * M + c] = val;
                if (STATS) { cs += val; cq += val * val; }
            }
        }
        if (STATS) {
            atomicAdd(&s_sum[cl], cs);
            atomicAdd(&s_sq[cl], cq);
        }
    }
    if (STATS) {
        __syncthreads();
        if (tid < BM) {
            const int c = col0 + tid;
            if (c < M) {
                atomicAdd(&gsum[c], s_sum[tid]);
                atomicAdd(&gsq[c], s_sq[tid]);
            }
        }
    }
}

// ============ weight conversion fp32 -> bf16 arena ============
#define W_G1 0
#define W_REL 49152
#define W_ROOT 180224
#define W_G2 311296
#define W_F1 409600
#define W_F2 507904
#define W_TOT 606208

__global__ __launch_bounds__(256) void convert_weights(
    const float* __restrict__ w0, const float* __restrict__ w1, const float* __restrict__ w2,
    const float* __restrict__ w3, const float* __restrict__ w4, const float* __restrict__ w5,
    unsigned short* __restrict__ out)
{
    int i = blockIdx.x * 256 + threadIdx.x;
    if (i >= W_TOT) return;
    const float* src; int off;
    if      (i < W_REL)  { src = w0; off = W_G1; }
    else if (i < W_ROOT) { src = w1; off = W_REL; }
    else if (i < W_G2)   { src = w2; off = W_ROOT; }
    else if (i < W_F1)   { src = w3; off = W_G2; }
    else if (i < W_F2)   { src = w4; off = W_F1; }
    else                 { src = w5; off = W_F2; }
    out[i] = f2bf(src[i - off]);
}

__global__ void bn_finalize(const float* __restrict__ sum, const float* __restrict__ sumsq,
                            float* __restrict__ mu, float* __restrict__ rs, int M, float invN)
{
    int i = blockIdx.x * blockDim.x + threadIdx.x;
    if (i < M) {
        float m = sum[i] * invN;
        float v = sumsq[i] * invN - m * m;
        mu[i] = m;
        rs[i] = rsqrtf(v + 1e-5f);
    }
}

// ============ BN apply variants (vectorized x4) ============
__global__ __launch_bounds__(256) void bn_apply_bf16(
    const float* __restrict__ pre, unsigned short* __restrict__ outb,
    int total4, int M4, const float* __restrict__ g, const float* __restrict__ b,
    const float* __restrict__ mu, const float* __restrict__ rs)
{
    for (int i = blockIdx.x * 256 + threadIdx.x; i < total4; i += gridDim.x * 256) {
        int c = (i % M4) * 4;
        float4 v = *(const float4*)&pre[(size_t)i * 4];
        float4 gv = *(const float4*)&g[c];
        float4 bv = *(const float4*)&b[c];
        float4 mv = *(const float4*)&mu[c];
        float4 rv = *(const float4*)&rs[c];
        ushort4 o;
        o.x = f2bf(gv.x * (v.x - mv.x) * rv.x + bv.x);
        o.y = f2bf(gv.y * (v.y - mv.y) * rv.y + bv.y);
        o.z = f2bf(gv.z * (v.z - mv.z) * rv.z + bv.z);
        o.w = f2bf(gv.w * (v.w - mv.w) * rv.w + bv.w);
        *(ushort4*)&outb[(size_t)i * 4] = o;
    }
}

__global__ __launch_bounds__(256) void bn_apply_gelu_bf16(
    const float* __restrict__ pre, unsigned short* __restrict__ outb,
    int total4, int M4, const float* __restrict__ g, const float* __restrict__ b,
    const float* __restrict__ mu, const float* __restrict__ rs)
{
    for (int i = blockIdx.x * 256 + threadIdx.x; i < total4; i += gridDim.x * 256) {
        int c = (i % M4) * 4;
        float4 v = *(const float4*)&pre[(size_t)i * 4];
        float4 gv = *(const float4*)&g[c];
        float4 bv = *(const float4*)&b[c];
        float4 mv = *(const float4*)&mu[c];
        float4 rv = *(const float4*)&rs[c];
        float t0 = gv.x * (v.x - mv.x) * rv.x + bv.x;
        float t1 = gv.y * (v.y - mv.y) * rv.y + bv.y;
        float t2 = gv.z * (v.z - mv.z) * rv.z + bv.z;
        float t3 = gv.w * (v.w - mv.w) * rv.w + bv.w;
        const float k = 0.70710678118654752f;
        ushort4 o;
        o.x = f2bf(0.5f * t0 * (1.f + erff(t0 * k)));
        o.y = f2bf(0.5f * t1 * (1.f + erff(t1 * k)));
        o.z = f2bf(0.5f * t2 * (1.f + erff(t2 * k)));
        o.w = f2bf(0.5f * t3 * (1.f + erff(t3 * k)));
        *(ushort4*)&outb[(size_t)i * 4] = o;
    }
}

__global__ __launch_bounds__(256) void bn_apply_res_bf16(
    const float* __restrict__ pre, const float* __restrict__ res,
    unsigned short* __restrict__ outb,
    int total4, int M4, const float* __restrict__ g, const float* __restrict__ b,
    const float* __restrict__ mu, const float* __restrict__ rs)
{
    for (int i = blockIdx.x * 256 + threadIdx.x; i < total4; i += gridDim.x * 256) {
        int c = (i % M4) * 4;
        float4 v = *(const float4*)&pre[(size_t)i * 4];
        float4 x = *(const float4*)&res[(size_t)i * 4];
        float4 gv = *(const float4*)&g[c];
        float4 bv = *(const float4*)&b[c];
        float4 mv = *(const float4*)&mu[c];
        float4 rv = *(const float4*)&rs[c];
        ushort4 o;
        o.x = f2bf(gv.x * (v.x - mv.x) * rv.x + bv.x + x.x);
        o.y = f2bf(gv.y * (v.y - mv.y) * rv.y + bv.y + x.y);
        o.z = f2bf(gv.z * (v.z - mv.z) * rv.z + bv.z + x.z);
        o.w = f2bf(gv.w * (v.w - mv.w) * rv.w + bv.w + x.w);
        *(ushort4*)&outb[(size_t)i * 4] = o;
    }
}

__global__ __launch_bounds__(256) void bn_apply_res_out(
    const float* __restrict__ pre, const unsigned short* __restrict__ resb,
    float* __restrict__ out,
    int total4, int M4, const float* __restrict__ g, const float* __restrict__ b,
    const float* __restrict__ mu, const float* __restrict__ rs)
{
    for (int i = blockIdx.x * 256 + threadIdx.x; i < total4; i += gridDim.x * 256) {
        int c = (i % M4) * 4;
        float4 v = *(const float4*)&pre[(size_t)i * 4];
        ushort4 x = *(const ushort4*)&resb[(size_t)i * 4];
        float4 gv = *(const float4*)&g[c];
        float4 bv = *(const float4*)&b[c];
        float4 mv = *(const float4*)&mu[c];
        float4 rv = *(const float4*)&rs[c];
        float4 o;
        o.x = gv.x * (v.x - mv.x) * rv.x + bv.x + b2f(x.x);
        o.y = gv.y * (v.y - mv.y) * rv.y + bv.y + b2f(x.y);
        o.z = gv.z * (v.z - mv.z) * rv.z + bv.z + b2f(x.z);
        o.w = gv.w * (v.w - mv.w) * rv.w + bv.w + b2f(x.w);
        *(float4*)&out[(size_t)i * 4] = o;
    }
}

// ============ CSR build: histogram, scan, fill ============
__global__ __launch_bounds__(256) void hist_count(
    const int* __restrict__ dst, int* __restrict__ cnt, int E)
{
    int e = blockIdx.x * blockDim.x + threadIdx.x;
    if (e < E) atomicAdd(&cnt[dst[e]], 1);
}

__global__ __launch_bounds__(256) void scan_block_sums(
    const int* __restrict__ cnt, int* __restrict__ partials, int n)
{
    __shared__ int sdata[256];
    int i = blockIdx.x * 256 + threadIdx.x;
    sdata[threadIdx.x] = (i < n) ? cnt[i] : 0;
    __syncthreads();
    for (int s = 128; s > 0; s >>= 1) {
        if (threadIdx.x < s) sdata[threadIdx.x] += sdata[threadIdx.x + s];
        __syncthreads();
    }
    if (threadIdx.x == 0) partials[blockIdx.x] = sdata[0];
}

__global__ void scan_partials(int* __restrict__ partials, int nb,
                              int* __restrict__ row_start, int n, int E)
{
    if (blockIdx.x == 0 && threadIdx.x == 0) {
        int acc = 0;
        for (int i = 0; i < nb; ++i) { int t = partials[i]; partials[i] = acc; acc += t; }
        row_start[n] = E;
    }
}

__global__ __launch_bounds__(256) void scan_final(
    const int* __restrict__ cnt, const int* __restrict__ partials,
    int* __restrict__ row_start, int n)
{
    __shared__ int sdata[256];
    int i = blockIdx.x * 256 + threadIdx.x;
    int v = (i < n) ? cnt[i] : 0;
    sdata[threadIdx.x] = v;
    __syncthreads();
    for (int s = 1; s < 256; s <<= 1) {
        int t = (threadIdx.x >= s) ? sdata[threadIdx.x - s] : 0;
        __syncthreads();
        sdata[threadIdx.x] += t;
        __syncthreads();
    }
    if (i < n) row_start[i] = partials[blockIdx.x] + sdata[threadIdx.x] - v;
}

__global__ __launch_bounds__(256) void csr_fill(
    const int* __restrict__ src, const int* __restrict__ dst,
    const int* __restrict__ row_start, int* __restrict__ cursor,
    int* __restrict__ srcs_sorted, int E)
{
    int e = blockIdx.x * blockDim.x + threadIdx.x;
    if (e < E) {
        int d = dst[e];
        int pos = row_start[d] + atomicAdd(&cursor[d], 1);
        srcs_sorted[pos] = src[e];
    }
}

// ============ gather-sum (bf16): AGG[n] = sum T[src], 256 ch ============
// one wave per node; half-waves process 2 edges concurrently (16B/lane),
// manual 2x unroll => 4 row loads in flight; final cross-half shfl reduce.
__global__ __launch_bounds__(256) void gather_sum(
    const int* __restrict__ row_start, const int* __restrict__ srcs,
    const unsigned short* __restrict__ T, unsigned short* __restrict__ AGG, int Nn)
{
    int n = blockIdx.x * 4 + (threadIdx.x >> 6);
    if (n >= Nn) return;
    const int lane = threadIdx.x & 63;
    const int half = lane >> 5;          // 0/1: which edge of the pair
    const int c0 = (lane & 31) * 8;      // 8 channels per lane
    const int e0 = row_start[n], e1 = row_start[n + 1];
    float a[8];
#pragma unroll
    for (int k = 0; k < 8; ++k) a[k] = 0.f;

    int e = e0 + half;
    for (; e + 2 < e1; e += 4) {
        int s0 = srcs[e], s1 = srcs[e + 2];
        u16x8 v0 = *(const u16x8*)&T[(size_t)s0 * 256 + c0];
        u16x8 v1 = *(const u16x8*)&T[(size_t)s1 * 256 + c0];
#pragma unroll
        for (int k = 0; k < 8; ++k) a[k] += b2f(v0[k]) + b2f(v1[k]);
    }
    for (; e < e1; e += 2) {
        int s = srcs[e];
        u16x8 v = *(const u16x8*)&T[(size_t)s * 256 + c0];
#pragma unroll
        for (int k = 0; k < 8; ++k) a[k] += b2f(v[k]);
    }
#pragma unroll
    for (int k = 0; k < 8; ++k) a[k] += __shfl_xor(a[k], 32);
    if (half == 0) {
        u16x8 o;
#pragma unroll
        for (int k = 0; k < 8; ++k) o[k] = f2bf(a[k]);
        *(u16x8*)&AGG[(size_t)n * 256 + c0] = o;
    }
}

// =====================================================================
extern "C" void kernel_launch(void* const* d_in, const int* in_sizes, int n_in,
                              void* d_out, int out_size, void* d_ws, size_t ws_size,
                              hipStream_t stream)
{
    const float* x        = (const float*)d_in[0];
    const int*   ei       = (const int*)d_in[1];
    const float* w_g1     = (const float*)d_in[2];
    const float* b_g1     = (const float*)d_in[3];
    const float* g1_gamma = (const float*)d_in[4];
    const float* g1_beta  = (const float*)d_in[5];
    const float* w_rel    = (const float*)d_in[6];
    const float* b_rel    = (const float*)d_in[7];
    const float* w_root   = (const float*)d_in[8];
    const float* w_g2     = (const float*)d_in[9];
    const float* b_g2     = (const float*)d_in[10];
    const float* g2_gamma = (const float*)d_in[11];
    const float* g2_beta  = (const float*)d_in[12];
    const float* w_f1     = (const float*)d_in[13];
    const float* b_f1     = (const float*)d_in[14];
    const float* f1_gamma = (const float*)d_in[15];
    const float* f1_beta  = (const float*)d_in[16];
    const float* w_f2     = (const float*)d_in[17];
    const float* b_f2     = (const float*)d_in[18];
    const float* f2_gamma = (const float*)d_in[19];
    const float* f2_beta  = (const float*)d_in[20];

    const int* src = ei;
    const int* dst = ei + EE;

    // workspace layout (~206 MB)
    char* p = (char*)d_ws;
    float* Pre = (float*)p;                     p += (size_t)NN * 512 * 4;  // shared fp32 pre-BN
    unsigned short* R2 = (unsigned short*)p;    p += (size_t)NN * 512 * 2;  // Hb then Fb
    unsigned short* R3 = (unsigned short*)p;    p += (size_t)NN * 256 * 2;  // Tb then X2b
    unsigned short* R4 = (unsigned short*)p;    p += (size_t)NN * 256 * 2;  // AGGb
    unsigned short* Wb = (unsigned short*)p;    p += 2 * 1024 * 1024;       // bf16 weights
    float* sum   = (float*)p;
    float* sumsq = sum + 512;
    float* mu    = sum + 1024;
    float* rs    = sum + 1536;

    unsigned short* Tb   = R3;
    unsigned short* AGGb = R4;
    unsigned short* Hb   = R2;
    unsigned short* X2b  = R3;
    unsigned short* Fb   = R2;

    // CSR scratch in Pre region (dead between BN-apply(T) and GEMM3)
    int* row_start   = (int*)Pre;            // NN+1
    int* cnt         = row_start + NN + 16;
    int* cursor      = cnt + NN;
    int* partials    = cursor + NN;
    int* srcs_sorted = partials + 256;       // EE

    float* out = (float*)d_out;
    const float invN = 1.f / (float)NN;
    dim3 blk(256);
    const int GY = (NN + 127) / 128;         // 391
    const int NB_SCAN = (NN + 255) / 256;    // 196

    auto zero_stats = [&]() {
        hipMemsetAsync(sum, 0, 1024 * sizeof(float), stream);
    };
    auto finalize = [&](int M) {
        hipLaunchKernelGGL(bn_finalize, dim3(2), dim3(256), 0, stream, sum, sumsq, mu, rs, M, invN);
    };

    // 0. weights -> bf16 arena
    hipLaunchKernelGGL(convert_weights, dim3((W_TOT + 255) / 256), blk, 0, stream,
                       w_g1, w_rel, w_root, w_g2, w_f1, w_f2, Wb);

    // ---- Grapher ----
    // 1. Pre = x @ w_g1^T + b_g1   [N,256]  + fused stats
    zero_stats();
    hipLaunchKernelGGL((gemm_mfma<true, false, false, true>), dim3(2, GY), blk, 0, stream,
                       (const void*)x, Wb + W_G1, nullptr, nullptr, b_g1, (void*)Pre,
                       sum, sumsq, NN, CC, 256);
    finalize(256);
    // 2-3. Tb = bf16(BN(Pre))
    hipLaunchKernelGGL(bn_apply_bf16, dim3(2048), blk, 0, stream, Pre, Tb,
                       NN * 64, 64, g1_gamma, g1_beta, mu, rs);
    // 4. CSR build + gather (AGGb = segsum(Tb[src]))
    hipMemsetAsync(cnt, 0, 2 * NN * sizeof(int), stream);
    hipLaunchKernelGGL(hist_count, dim3((EE + 255) / 256), blk, 0, stream, dst, cnt, EE);
    hipLaunchKernelGGL(scan_block_sums, dim3(NB_SCAN), blk, 0, stream, cnt, partials, NN);
    hipLaunchKernelGGL(scan_partials, dim3(1), dim3(64), 0, stream, partials, NB_SCAN,
                       row_start, NN, EE);
    hipLaunchKernelGGL(scan_final, dim3(NB_SCAN), blk, 0, stream, cnt, partials, row_start, NN);
    hipLaunchKernelGGL(csr_fill, dim3((EE + 255) / 256), blk, 0, stream, src, dst,
                       row_start, cursor, srcs_sorted, EE);
    hipLaunchKernelGGL(gather_sum, dim3((NN + 3) / 4), blk, 0, stream,
                       row_start, srcs_sorted, Tb, AGGb, NN);
    // 5. Hb = bf16(AGGb @ w_rel^T + b_rel + Tb @ w_root^T)   [N,512]  (no BN)
    hipLaunchKernelGGL((gemm_mfma<false, true, true, false>), dim3(4, GY), blk, 0, stream,
                       (const void*)AGGb, Wb + W_REL, (const void*)Tb, Wb + W_ROOT,
                       b_rel, (void*)Hb, nullptr, nullptr, NN, 256, 512);
    // 6. Pre = Hb @ w_g2^T + b_g2   [N,192]  + fused stats
    zero_stats();
    hipLaunchKernelGGL((gemm_mfma<false, false, false, true>), dim3(2, GY), blk, 0, stream,
                       (const void*)Hb, Wb + W_G2, nullptr, nullptr, b_g2, (void*)Pre,
                       sum, sumsq, NN, 512, CC);
    finalize(CC);
    // 7-8. X2b = bf16(BN(Pre) + x)
    hipLaunchKernelGGL(bn_apply_res_bf16, dim3(2048), blk, 0, stream, Pre, x, X2b,
                       NN * 48, 48, g2_gamma, g2_beta, mu, rs);
    // ---- FFN ----
    // 9. Pre = X2b @ w_f1^T + b_f1   [N,512]  + fused stats
    zero_stats();
    hipLaunchKernelGGL((gemm_mfma<false, false, false, true>), dim3(4, GY), blk, 0, stream,
                       (const void*)X2b, Wb + W_F1, nullptr, nullptr, b_f1, (void*)Pre,
                       sum, sumsq, NN, CC, 512);
    finalize(512);
    // 10-11. Fb = bf16(gelu(BN(Pre)))
    hipLaunchKernelGGL(bn_apply_gelu_bf16, dim3(2048), blk, 0, stream, Pre, Fb,
                       NN * 128, 128, f1_gamma, f1_beta, mu, rs);
    // 12. Pre = Fb @ w_f2^T + b_f2   [N,192]  + fused stats
    zero_stats();
    hipLaunchKernelGGL((gemm_mfma<false, false, false, true>), dim3(2, GY), blk, 0, stream,
                       (const void*)Fb, Wb + W_F2, nullptr, nullptr, b_f2, (void*)Pre,
                       sum, sumsq, NN, 512, CC);
    finalize(CC);
    // 13-14. out = BN(Pre) + X2b
    hipLaunchKernelGGL(bn_apply_res_out, dim3(2048), blk, 0, stream, Pre, X2b, out,
                       NN * 48, 48, f2_gamma, f2_beta, mu, rs);

    (void)in_sizes; (void)n_in; (void)out_size; (void)ws_size;
}